// Round 10
// baseline (46.295 us; speedup 1.0000x reference)
//
#include <hip/hip_runtime.h>
#include <math.h>

#define NB 36
#define W 640
#define H 640
#define NSAMP 64
#define RPB 20                     // rows per block
#define BPS 32                     // blocks per sample (32*20 = 640)
#define NBLK (NSAMP * BPS)         // 2048 = 8 blocks/CU, fully resident
#define FIX_SCALE 4194304.0f       // 2^22: row prefix < 640*2^22 < 2^32
#define INV_FIX (1.0f/4194304.0f)
#define CNT_SHIFT 44               // sample-bin sum < 2^40.7 < 2^44
#define SUM_MASK ((1ull << CNT_SHIFT) - 1)
#define AMB 1e-6

// cot((m-18)*pi/18) — compile-time, <1e-16 rel err; deviations from libm
// (~1e-13 px on cutpoints) only matter inside the AMB razor band, where
// bin_slow (exact golden) decides. Validated R9 (absmax=0).
__device__ __constant__ double COT[36] = {
    0.0,
    5.6712818196177095,  2.7474774194546223,  1.7320508075688773,
    1.1917535925942100,  0.8390996311772800,  0.5773502691896258,
    0.3639702342662024,  0.1763269807084650,  0.0,
    -0.1763269807084650, -0.3639702342662024, -0.5773502691896258,
    -0.8390996311772800, -1.1917535925942100, -1.7320508075688773,
    -2.7474774194546223, -5.6712818196177095,
    0.0,
    5.6712818196177095,  2.7474774194546223,  1.7320508075688773,
    1.1917535925942100,  0.8390996311772800,  0.5773502691896258,
    0.3639702342662024,  0.1763269807084650,  0.0,
    -0.1763269807084650, -0.3639702342662024, -0.5773502691896258,
    -0.8390996311772800, -1.1917535925942100, -1.7320508075688773,
    -2.7474774194546223, -5.6712818196177095
};

// Exact f64 golden chain (validated: absmax==0 in rounds 3-9).
__device__ __forceinline__ int bin_slow(int x, int y, double cxd, double cyd) {
    const double PI_D    = 3.141592653589793;
    const double TWOPI_D = 6.283185307179586;
    double t  = (atan2((double)y - cyd, (double)x - cxd) + PI_D) / TWOPI_D;
    double bd = t * 36.0;
    int k = (int)bd;
    k = k < 0 ? 0 : k;
    return k > NB - 1 ? NB - 1 : k;
}

// one DPP scan step: x += shifted(x)  (validated rounds 7-9)
#define SCAN_STEP(x, ctrl, rmask)                                             \
    x += (unsigned)__builtin_amdgcn_update_dpp(0, (int)(x), (ctrl), (rmask),  \
                                               0xf, false)

__global__ __launch_bounds__(256, 8) void acl_main(const float* __restrict__ mask,
                                                   const float* __restrict__ bbox,
                                                   unsigned long long* __restrict__ ws) {
    __shared__ int A_l[RPB][18];               // ascending segment right-ends
    __shared__ int sgn_l[RPB];                 // sign(dy) per row
    __shared__ __align__(16) unsigned srow[4][768];  // per-wave prefix image
    __shared__ unsigned long long lbin[NB];

    const int tid = threadIdx.x;
    const int b   = blockIdx.x >> 5;           // sample
    const int rg  = blockIdx.x & (BPS - 1);    // 20-row group
    const int y0  = rg * RPB;

    if (tid < NB) lbin[tid] = 0ull;
    if (tid < RPB) A_l[tid][17] = W - 1;       // sentinel

    const double cxd = (double)bbox[b * 4 + 0] * 640.0;   // exact in f64
    const double cyd = (double)bbox[b * 4 + 1] * 640.0;

    // ---- phase 1: 20 rows x 17 cutpoints (validated razor logic) ---------
    for (int task = tid; task < RPB * 17; task += 256) {
        const int rl = task / 17, mi = task % 17;
        const int y  = y0 + rl;
        const double dy = (double)y - cyd;
        int i, a;
        if (dy == 0.0) {
            if (mi == 0) sgn_l[rl] = 0;
            i = mi;
            a = (mi == 0) ? ((int)ceil(cxd) - 1) : (W - 1);
        } else {
            const bool dp = (dy > 0.0);
            if (mi == 0) sgn_l[rl] = dp ? 1 : -1;
            const int m = dp ? (19 + mi) : (1 + mi);
            double x = cxd + dy * COT[m];
            x = fmin(fmax(x, -2.0), 642.0);
            double g  = x + 2.0;
            int    gi = (int)g;
            double fr = g - (double)gi;
            int v = dp ? (gi - 2)    // floor(x): max px with bin >= m
                       : (gi - 1);   // ceil(x):  min px with bin >= m
            if (fr < AMB || fr > 1.0 - AMB) {
                int xa = (int)(x + 2.5) - 2;
                if (xa >= 0 && xa <= W - 1) {
                    int kb = bin_slow(xa, y, cxd, cyd);
                    if (dp) v = (kb >= m) ? xa : xa - 1;
                    else    v = (kb >= m) ? xa : xa + 1;
                }
            }
            if (dp) { i = 16 - mi; a = v; }      // ascending index
            else    { i = mi;      a = v - 1; }
        }
        a = a < -1 ? -1 : (a > W - 1 ? W - 1 : a);
        A_l[rl][i] = a;
    }
    __syncthreads();

    // ---- phase 2: each wave streams 5 rows, depth-1 prefetch -------------
    const int wid = tid >> 6, lane = tid & 63;
    const float* rowbase = mask + (size_t)b * (W * H) + (size_t)y0 * W;

    unsigned long long accPs = 0ull, accNs = 0ull;
    unsigned accPc = 0u, accNc = 0u;

    const float4 z4 = make_float4(0.f, 0.f, 0.f, 0.f);
    const float4* rp0 = (const float4*)(rowbase + (size_t)wid * W);
    float4 a0 = rp0[lane], a1 = rp0[lane + 64];
    float4 a2 = (lane < 32) ? rp0[lane + 128] : z4;

    for (int j = 0; j < 5; j++) {
        const int rl = wid + 4 * j;
        float4 n0, n1, n2;
        if (j < 4) {                           // prefetch next row
            const float4* np = (const float4*)(rowbase + (size_t)(rl + 4) * W);
            n0 = np[lane];
            n1 = np[lane + 64];
            n2 = (lane < 32) ? np[lane + 128] : z4;
        }

        unsigned carry = 0u;
        #pragma unroll
        for (int s = 0; s < 3; s++) {
            const float4 v = (s == 0) ? a0 : (s == 1) ? a1 : a2;
            const unsigned q0 = __float2uint_rn(v.x * FIX_SCALE);
            const unsigned q1 = __float2uint_rn(v.y * FIX_SCALE);
            const unsigned q2 = __float2uint_rn(v.z * FIX_SCALE);
            const unsigned q3 = __float2uint_rn(v.w * FIX_SCALE);
            const unsigned p0 = q0, p1 = p0 + q1, p2 = p1 + q2, p3 = p2 + q3;

            unsigned x = p3;                   // 64-lane inclusive scan (VALU)
            SCAN_STEP(x, 0x111, 0xf);          // row_shr:1
            SCAN_STEP(x, 0x112, 0xf);          // row_shr:2
            SCAN_STEP(x, 0x114, 0xf);          // row_shr:4
            SCAN_STEP(x, 0x118, 0xf);          // row_shr:8
            SCAN_STEP(x, 0x142, 0xa);          // row_bcast:15
            SCAN_STEP(x, 0x143, 0xc);          // row_bcast:31
            const unsigned base = carry + (x - p3);
            uint4 wv;
            wv.x = base + p0; wv.y = base + p1; wv.z = base + p2; wv.w = base + p3;
            *((uint4*)&srow[wid][s * 256 + lane * 4]) = wv;   // wave-private
            carry += (unsigned)__builtin_amdgcn_readlane((int)x, 63);
        }

        if (lane < 18) {                       // wave-private segment extract
            const int aR = A_l[rl][lane];
            const int aL = (lane == 0) ? -1 : A_l[rl][lane - 1];
            const int cnt = aR - aL;
            if (cnt > 0) {                     // cnt>0 => aR >= 0
                const unsigned sR = srow[wid][aR];
                const unsigned sL = (aL >= 0) ? srow[wid][aL] : 0u;
                const unsigned seg = sR - sL;
                const int sg = sgn_l[rl];
                if (sg > 0)      { accPc += (unsigned)cnt; accPs += seg; }
                else if (sg < 0) { accNc += (unsigned)cnt; accNs += seg; }
                else atomicAdd(&lbin[(lane == 0) ? 35 : 18],
                               ((unsigned long long)cnt << CNT_SHIFT)
                               + (unsigned long long)seg);
            }
        }
        if (j < 4) { a0 = n0; a1 = n1; a2 = n2; }
    }

    // ---- flush: regs -> lbin -> transposed per-block partial slab --------
    if (lane < 18) {
        if (accPc) atomicAdd(&lbin[35 - lane],
                             ((unsigned long long)accPc << CNT_SHIFT) + accPs);
        if (accNc) atomicAdd(&lbin[lane],
                             ((unsigned long long)accNc << CNT_SHIFT) + accNs);
    }
    __syncthreads();
    if (tid < NB)
        ws[(size_t)tid * NBLK + blockIdx.x] = lbin[tid];   // plain store
}

__global__ __launch_bounds__(256) void acl_final(const unsigned long long* __restrict__ ws,
                                                 float* __restrict__ out) {
    __shared__ unsigned nund[256];
    __shared__ float s[NSAMP];
    const int tid = threadIdx.x;
    const int b = tid & 63, q = tid >> 6;      // sample, bin-quarter
    unsigned cu = 0;
    #pragma unroll
    for (int kk = 0; kk < 9; kk++) {
        const int k = q * 9 + kk;
        const unsigned long long* base = ws + (size_t)k * NBLK + (size_t)b * BPS;
        unsigned long long t0 = 0ull, t1 = 0ull;
        #pragma unroll
        for (int g = 0; g < BPS; g += 2) {     // 256B contiguous, coalesced
            t0 += base[g];
            t1 += base[g + 1];
        }
        const unsigned long long tot = t0 + t1;
        const unsigned long long cnt = tot >> CNT_SHIFT;
        const float sum = (float)(tot & SUM_MASK) * INV_FIX;
        const float act = (cnt != 0ull) ? (sum / (float)cnt) : 0.0f;
        if (act < 0.1f) cu++;
    }
    nund[tid] = cu;
    __syncthreads();
    if (tid < NSAMP) {
        const unsigned n = nund[tid] + nund[64 + tid] + nund[128 + tid] + nund[192 + tid];
        s[tid] = (float)n / 36.0f;             // same float chain as rounds 3-9
    }
    __syncthreads();
    if (tid == 0) {
        float acc = 0.0f;
        for (int i = 0; i < NSAMP; i++) acc += s[i];
        out[0] = acc / 64.0f;                  // PENALTY_WEIGHT == 1
    }
}

extern "C" void kernel_launch(void* const* d_in, const int* in_sizes, int n_in,
                              void* d_out, int out_size, void* d_ws, size_t ws_size,
                              hipStream_t stream) {
    const float* mask = (const float*)d_in[0];
    const float* bbox = (const float*)d_in[1];
    unsigned long long* ws = (unsigned long long*)d_ws;

    acl_main<<<dim3(NBLK), dim3(256), 0, stream>>>(mask, bbox, ws);
    acl_final<<<dim3(1), dim3(256), 0, stream>>>(ws, (float*)d_out);
}

// Round 11
// 34.245 us; speedup vs baseline: 1.3519x; 1.3519x over previous
//
#include <hip/hip_runtime.h>
#include <math.h>

#define NB 36
#define W 640
#define H 640
#define NSAMP 64
#define RPB 40                     // rows per block
#define BPS 16                     // blocks per sample (16*40 = 640)
#define NBLK (NSAMP * BPS)         // 1024
#define FIX_SCALE 4194304.0f       // 2^22: row prefix < 640*2^22 < 2^32
#define INV_FIX (1.0f/4194304.0f)
#define CNT_SHIFT 44               // sample-bin sum < 2^40.7 < 2^44
#define SUM_MASK ((1ull << CNT_SHIFT) - 1)
#define AMB 1e-6

// cot((m-18)*pi/18) — compile-time, <1e-16 rel err; deviations from libm
// (~1e-13 px on cutpoints) only matter inside the AMB razor band, where
// bin_slow (exact golden) decides. Validated R9/R10 (absmax=0).
__device__ __constant__ double COT[36] = {
    0.0,
    5.6712818196177095,  2.7474774194546223,  1.7320508075688773,
    1.1917535925942100,  0.8390996311772800,  0.5773502691896258,
    0.3639702342662024,  0.1763269807084650,  0.0,
    -0.1763269807084650, -0.3639702342662024, -0.5773502691896258,
    -0.8390996311772800, -1.1917535925942100, -1.7320508075688773,
    -2.7474774194546223, -5.6712818196177095,
    0.0,
    5.6712818196177095,  2.7474774194546223,  1.7320508075688773,
    1.1917535925942100,  0.8390996311772800,  0.5773502691896258,
    0.3639702342662024,  0.1763269807084650,  0.0,
    -0.1763269807084650, -0.3639702342662024, -0.5773502691896258,
    -0.8390996311772800, -1.1917535925942100, -1.7320508075688773,
    -2.7474774194546223, -5.6712818196177095
};

// Exact f64 golden chain (validated: absmax==0 in rounds 3-10).
__device__ __forceinline__ int bin_slow(int x, int y, double cxd, double cyd) {
    const double PI_D    = 3.141592653589793;
    const double TWOPI_D = 6.283185307179586;
    double t  = (atan2((double)y - cyd, (double)x - cxd) + PI_D) / TWOPI_D;
    double bd = t * 36.0;
    int k = (int)bd;
    k = k < 0 ? 0 : k;
    return k > NB - 1 ? NB - 1 : k;
}

// one DPP scan step: x += shifted(x)  (validated rounds 7-10)
#define SCAN_STEP(x, ctrl, rmask)                                             \
    x += (unsigned)__builtin_amdgcn_update_dpp(0, (int)(x), (ctrl), (rmask),  \
                                               0xf, false)

__global__ __launch_bounds__(256) void acl_main(const float* __restrict__ mask,
                                                const float* __restrict__ bbox,
                                                unsigned long long* __restrict__ ws) {
    __shared__ int A_l[RPB][18];               // ascending segment right-ends
    __shared__ int sgn_l[RPB];                 // sign(dy) per row
    __shared__ __align__(16) unsigned srow[4][768];  // per-wave prefix image
    __shared__ unsigned long long lbin[NB];

    const int tid = threadIdx.x;
    const int b   = blockIdx.x >> 4;           // sample
    const int rg  = blockIdx.x & (BPS - 1);    // 40-row group
    const int y0  = rg * RPB;

    if (tid < NB) lbin[tid] = 0ull;
    if (tid < RPB) A_l[tid][17] = W - 1;       // sentinel

    const double cxd = (double)bbox[b * 4 + 0] * 640.0;   // exact in f64
    const double cyd = (double)bbox[b * 4 + 1] * 640.0;

    // ---- phase 1: 40 rows x 17 cutpoints (validated razor logic) ---------
    for (int task = tid; task < RPB * 17; task += 256) {
        const int rl = task / 17, mi = task % 17;
        const int y  = y0 + rl;
        const double dy = (double)y - cyd;
        int i, a;
        if (dy == 0.0) {
            if (mi == 0) sgn_l[rl] = 0;
            i = mi;
            a = (mi == 0) ? ((int)ceil(cxd) - 1) : (W - 1);
        } else {
            const bool dp = (dy > 0.0);
            if (mi == 0) sgn_l[rl] = dp ? 1 : -1;
            const int m = dp ? (19 + mi) : (1 + mi);
            double x = cxd + dy * COT[m];
            x = fmin(fmax(x, -2.0), 642.0);
            double g  = x + 2.0;
            int    gi = (int)g;
            double fr = g - (double)gi;
            int v = dp ? (gi - 2)    // floor(x): max px with bin >= m
                       : (gi - 1);   // ceil(x):  min px with bin >= m
            if (fr < AMB || fr > 1.0 - AMB) {
                int xa = (int)(x + 2.5) - 2;
                if (xa >= 0 && xa <= W - 1) {
                    int kb = bin_slow(xa, y, cxd, cyd);
                    if (dp) v = (kb >= m) ? xa : xa - 1;
                    else    v = (kb >= m) ? xa : xa + 1;
                }
            }
            if (dp) { i = 16 - mi; a = v; }      // ascending index
            else    { i = mi;      a = v - 1; }
        }
        a = a < -1 ? -1 : (a > W - 1 ? W - 1 : a);
        A_l[rl][i] = a;
    }
    __syncthreads();

    // ---- phase 2: each wave streams 10 rows, depth-2 prefetch ------------
    const int wid = tid >> 6, lane = tid & 63;
    const float* rowbase = mask + (size_t)b * (W * H) + (size_t)y0 * W;

    unsigned long long accPs = 0ull, accNs = 0ull;
    unsigned accPc = 0u, accNc = 0u;

    const float4 z4 = make_float4(0.f, 0.f, 0.f, 0.f);
    const float4* rpA = (const float4*)(rowbase + (size_t)wid * W);
    float4 a0 = rpA[lane], a1 = rpA[lane + 64];
    float4 a2 = (lane < 32) ? rpA[lane + 128] : z4;
    const float4* rpB = (const float4*)(rowbase + (size_t)(wid + 4) * W);
    float4 b0 = rpB[lane], b1 = rpB[lane + 64];
    float4 b2 = (lane < 32) ? rpB[lane + 128] : z4;

    for (int j = 0; j < 10; j++) {
        const int rl = wid + 4 * j;
        float4 n0 = z4, n1 = z4, n2 = z4;
        if (j < 8) {                           // prefetch row j+2
            const float4* np = (const float4*)(rowbase + (size_t)(rl + 8) * W);
            n0 = np[lane];
            n1 = np[lane + 64];
            n2 = (lane < 32) ? np[lane + 128] : z4;
        }

        unsigned carry = 0u;
        #pragma unroll
        for (int s = 0; s < 3; s++) {
            const float4 v = (s == 0) ? a0 : (s == 1) ? a1 : a2;
            const unsigned q0 = __float2uint_rn(v.x * FIX_SCALE);
            const unsigned q1 = __float2uint_rn(v.y * FIX_SCALE);
            const unsigned q2 = __float2uint_rn(v.z * FIX_SCALE);
            const unsigned q3 = __float2uint_rn(v.w * FIX_SCALE);
            const unsigned p0 = q0, p1 = p0 + q1, p2 = p1 + q2, p3 = p2 + q3;

            unsigned x = p3;                   // 64-lane inclusive scan (VALU)
            SCAN_STEP(x, 0x111, 0xf);          // row_shr:1
            SCAN_STEP(x, 0x112, 0xf);          // row_shr:2
            SCAN_STEP(x, 0x114, 0xf);          // row_shr:4
            SCAN_STEP(x, 0x118, 0xf);          // row_shr:8
            SCAN_STEP(x, 0x142, 0xa);          // row_bcast:15
            SCAN_STEP(x, 0x143, 0xc);          // row_bcast:31
            const unsigned base = carry + (x - p3);
            uint4 wv;
            wv.x = base + p0; wv.y = base + p1; wv.z = base + p2; wv.w = base + p3;
            *((uint4*)&srow[wid][s * 256 + lane * 4]) = wv;   // wave-private
            carry += (unsigned)__builtin_amdgcn_readlane((int)x, 63);
        }

        if (lane < 18) {                       // wave-private segment extract
            const int aR = A_l[rl][lane];
            const int aL = (lane == 0) ? -1 : A_l[rl][lane - 1];
            const int cnt = aR - aL;
            if (cnt > 0) {                     // cnt>0 => aR >= 0
                const unsigned sR = srow[wid][aR];
                const unsigned sL = (aL >= 0) ? srow[wid][aL] : 0u;
                const unsigned seg = sR - sL;
                const int sg = sgn_l[rl];
                if (sg > 0)      { accPc += (unsigned)cnt; accPs += seg; }
                else if (sg < 0) { accNc += (unsigned)cnt; accNs += seg; }
                else atomicAdd(&lbin[(lane == 0) ? 35 : 18],
                               ((unsigned long long)cnt << CNT_SHIFT)
                               + (unsigned long long)seg);
            }
        }
        a0 = b0; a1 = b1; a2 = b2;
        b0 = n0; b1 = n1; b2 = n2;
    }

    // ---- flush: regs -> lbin -> transposed partial slab (plain stores) ---
    if (lane < 18) {
        if (accPc) atomicAdd(&lbin[35 - lane],
                             ((unsigned long long)accPc << CNT_SHIFT) + accPs);
        if (accNc) atomicAdd(&lbin[lane],
                             ((unsigned long long)accNc << CNT_SHIFT) + accNs);
    }
    __syncthreads();
    if (tid < NB)
        ws[(size_t)tid * NBLK + blockIdx.x] = lbin[tid];
}

__global__ __launch_bounds__(256) void acl_final(const unsigned long long* __restrict__ ws,
                                                 float* __restrict__ out) {
    __shared__ unsigned nund[256];
    __shared__ float s[NSAMP];
    const int tid = threadIdx.x;
    const int b = tid & 63, q = tid >> 6;      // sample, bin-quarter
    unsigned cu = 0;
    #pragma unroll
    for (int kk = 0; kk < 9; kk++) {
        const int k = q * 9 + kk;
        const unsigned long long* base = ws + (size_t)k * NBLK + (size_t)b * BPS;
        unsigned long long t0 = 0ull, t1 = 0ull;
        #pragma unroll
        for (int g = 0; g < BPS; g += 2) {     // 128B contiguous, coalesced
            t0 += base[g];
            t1 += base[g + 1];
        }
        const unsigned long long tot = t0 + t1;
        const unsigned long long cnt = tot >> CNT_SHIFT;
        const float sum = (float)(tot & SUM_MASK) * INV_FIX;
        const float act = (cnt != 0ull) ? (sum / (float)cnt) : 0.0f;
        if (act < 0.1f) cu++;
    }
    nund[tid] = cu;
    __syncthreads();
    if (tid < NSAMP) {
        const unsigned n = nund[tid] + nund[64 + tid] + nund[128 + tid] + nund[192 + tid];
        s[tid] = (float)n / 36.0f;             // same float chain as rounds 3-10
    }
    __syncthreads();
    if (tid == 0) {
        float acc = 0.0f;
        for (int i = 0; i < NSAMP; i++) acc += s[i];
        out[0] = acc / 64.0f;                  // PENALTY_WEIGHT == 1
    }
}

extern "C" void kernel_launch(void* const* d_in, const int* in_sizes, int n_in,
                              void* d_out, int out_size, void* d_ws, size_t ws_size,
                              hipStream_t stream) {
    const float* mask = (const float*)d_in[0];
    const float* bbox = (const float*)d_in[1];
    unsigned long long* ws = (unsigned long long*)d_ws;

    acl_main<<<dim3(NBLK), dim3(256), 0, stream>>>(mask, bbox, ws);
    acl_final<<<dim3(1), dim3(256), 0, stream>>>(ws, (float*)d_out);
}